// Round 11
// baseline (118.277 us; speedup 1.0000x reference)
//
#include <hip/hip_runtime.h>

// Involution (RedNet-style), N=4 C=256 H=W=56, K=7, G=16, ratio=4 (Cr=64).
// k0: fold BN into w1f/bf (coalesced reads); repack w2 -> w2t[g][kh][o][8].
// k1: conv1 GEMM; x-tile staged in LDS, 8 waves x 8 outputs, s_load weights.
// k2: fused kernel-gen + involution, all-LDS streaming:
//     - t tile packed float2 in LDS (16 KB)
//     - x tile staged ZERO-PADDED as float2 [8 c2][8 rows][64 cols] (32 KB)
//       -> Phase B has no masks/clamps: ds_read_b64 @ immediate offsets + FMA
//     - ker[14] (both kh of this wave) computed upfront from SGPR weight rows
//     - conflict-free float4 stride-5 cross-wave reduction (aliased LDS)

#define CONST_AS __attribute__((address_space(4)))

namespace {
constexpr int Nn  = 4;
constexpr int Cc  = 256;
constexpr int Hh  = 56;
constexpr int Ww  = 56;
constexpr int HW  = Hh * Ww;        // 3136
constexpr int NPX = Nn * HW;        // 12544
constexpr int Cr  = 64;             // reduced channels
constexpr int Gg  = 16;             // groups

// workspace layout (floats)
constexpr size_t WS_W1F = 0;                          // [256][64]
constexpr size_t WS_BF  = WS_W1F + (size_t)Cc * Cr;   // [64]
constexpr size_t WS_W2T = WS_BF  + Cr;                // [16][7][64][8]
constexpr size_t WS_T   = WS_W2T + (size_t)Gg * 7 * Cr * 8;  // [64][12544]

// CK-style cast to constant address space: uniform loads become s_load_*.
__device__ __forceinline__ const CONST_AS float* cptr(const float* p) {
    return (const CONST_AS float*)(unsigned long long)p;
}
}

// ---------------------------------------------------------------------------
// k0: weight prep, all reads coalesced.
//   w1f[c][o] = w1[o][c]*sc[o];  bf[o] = folded bias;
//   w2t[g][kh][o][j] = w2[g*49+kh*7+j][o] (j<7), [..][7] = 0.
// ---------------------------------------------------------------------------
__global__ void __launch_bounds__(256)
k0_prep(const float* __restrict__ w1, const float* __restrict__ b1,
        const float* __restrict__ gamma, const float* __restrict__ beta,
        const float* __restrict__ mean,  const float* __restrict__ var,
        const float* __restrict__ w2,
        float* __restrict__ w1f, float* __restrict__ bf, float* __restrict__ w2t)
{
    const int id = blockIdx.x * 256 + threadIdx.x;           // 0 .. 65535
    if (id < Cc * Cr) {                                      // w1 read coalesced
        const int o = id >> 8, c = id & 255;
        const float sc = gamma[o] * rsqrtf(var[o] + 1e-5f);
        w1f[c * Cr + o] = w1[id] * sc;
    }
    if (id < Cr)
        bf[id] = fmaf(b1[id] - mean[id], gamma[id] * rsqrtf(var[id] + 1e-5f),
                      beta[id]);
    if (id < Gg * 49 * Cr) {                                 // w2 read coalesced
        const int o = id & 63, kidx = id >> 6;               // kidx = g*49+kh*7+j
        const int g = kidx / 49, r = kidx - g * 49;
        const int kh = r / 7, j = r - kh * 7;
        w2t[g * 3584 + kh * 512 + o * 8 + j] = w2[id];
    }
    if (id < Gg * 7 * Cr) {                                  // zero pad j=7
        const int g = id / 448, r = id - g * 448;
        const int kh = r >> 6, o = r & 63;
        w2t[g * 3584 + kh * 512 + o * 8 + 7] = 0.f;
    }
}

// ---------------------------------------------------------------------------
// k1: 1x1 conv + folded BN + ReLU.
// grid (196) x 512. Block stages x-tile [256 c][64 px] in LDS (64 KB);
// wave q computes o = q*8 .. +8 from LDS against s_load weight rows.
// ---------------------------------------------------------------------------
__global__ void __launch_bounds__(512)
k1_conv_bn_relu(const float* __restrict__ x, const float* __restrict__ w1f,
                const float* __restrict__ bf, float* __restrict__ t)
{
    __shared__ float xs[Cc][64];                             // 64 KB

    const int tid  = threadIdx.x;
    const int lane = tid & 63;
    const int q    = __builtin_amdgcn_readfirstlane(tid >> 6);   // 0..7
    const int tile = __builtin_amdgcn_readfirstlane((int)blockIdx.x); // 0..195
    const int n    = __builtin_amdgcn_readfirstlane(tile / 49);
    const int hwb  = __builtin_amdgcn_readfirstlane((tile - n * 49) * 64);
    const int px   = tile * 64 + lane;

    const float* xb = x + (size_t)n * Cc * HW + hwb + lane;
    float v[32];
#pragma unroll
    for (int i = 0; i < 32; ++i)
        v[i] = xb[(size_t)(q + 8 * i) * HW];                 // coalesced
#pragma unroll
    for (int i = 0; i < 32; ++i)
        xs[q + 8 * i][lane] = v[i];
    __syncthreads();

    const int o0 = q * 8;
    const CONST_AS float* wf = cptr(w1f) + o0;
    float acc[8];
#pragma unroll
    for (int i = 0; i < 8; ++i) acc[i] = 0.f;

#pragma unroll 4
    for (int c = 0; c < Cc; ++c) {
        const float xv = xs[c][lane];                        // 2-way, free
        const CONST_AS float* wr = wf + c * Cr;              // s_load_dwordx8
#pragma unroll
        for (int i = 0; i < 8; ++i)
            acc[i] = fmaf(xv, wr[i], acc[i]);
    }

    const CONST_AS float* bfc = cptr(bf) + o0;
#pragma unroll
    for (int i = 0; i < 8; ++i) {
        const float vv = acc[i] + bfc[i];
        t[(size_t)(o0 + i) * NPX + px] = vv > 0.f ? vv : 0.f;  // coalesced
    }
}

// ---------------------------------------------------------------------------
// k2: fused kernel-gen + involution, all-LDS streaming.
// grid (196, 16) x 256. block = (px-tile, g); wave wv owns kh {wv, wv+4}.
// ---------------------------------------------------------------------------
__global__ void __launch_bounds__(256)
k2_involution(const float* __restrict__ x, const float* __restrict__ t,
              const float* __restrict__ w2t, const float* __restrict__ b2,
              float* __restrict__ out)
{
    __shared__ __align__(16) float smem[12288];              // 48 KB
    float2* xs2 = (float2*)smem;                             // [8 c2][8 rr][64 col]
    float*  tsw = smem + 8192;                               // t packed: 4096 floats

    const int tid  = threadIdx.x;
    const int lane = tid & 63;
    const int wv   = __builtin_amdgcn_readfirstlane(tid >> 6);          // 0..3
    const int tile = __builtin_amdgcn_readfirstlane((int)blockIdx.x);   // 0..195
    const int g    = __builtin_amdgcn_readfirstlane((int)blockIdx.y);
    const int n    = __builtin_amdgcn_readfirstlane(tile / 49);
    const int base = __builtin_amdgcn_readfirstlane(tile * 64 - n * HW);
    const int r0   = __builtin_amdgcn_readfirstlane(base / Ww);
    const int px   = tile * 64 + lane;
    const int hw   = base + lane;
    const int h    = hw / Ww;                                // per-lane
    const int w    = hw - h * Ww;
    const int hrel = h - r0;                                 // 0 or 1

    // ---- stage t (packed float2 pairs) ----
    {
        const float* tb = t + px;
        float v[16];
#pragma unroll
        for (int i = 0; i < 16; ++i)
            v[i] = tb[(size_t)(wv + 4 * i) * NPX];           // coalesced
#pragma unroll
        for (int i = 0; i < 16; ++i) {
            const int o = wv + 4 * i;
            tsw[(o >> 1) * 128 + lane * 2 + (o & 1)] = v[i];
        }
    }

    // ---- stage x, zero-padded: xs2[c2][rr][col] = x[g16+2c2(+1)][r0-3+rr][col-3] ----
    {
        const float* xgb = x + (size_t)n * Cc * HW + (size_t)(g * 16) * HW;
#pragma unroll
        for (int i = 0; i < 16; ++i) {
            const int f   = tid + i * 256;                   // 4096 slots
            const int c2  = f >> 9;
            const int rr  = (f >> 6) & 7;
            const int col = f & 63;
            const int hh  = r0 - 3 + rr;
            const int cc  = col - 3;
            const bool ok = (hh >= 0) & (hh < Hh) & (cc >= 0) & (cc < Ww);
            const int off = ok ? (c2 * 2 * HW + hh * Ww + cc) : 0;
            const float a = ok ? xgb[off] : 0.f;
            const float b = ok ? xgb[off + HW] : 0.f;
            xs2[f] = make_float2(a, b);
        }
    }
    __syncthreads();

    // ---- Phase A: ker[14] for kh = wv and wv+4 (wv=3: second half junk) ----
    float ker[14];
    {
        const CONST_AS float* b2g = cptr(b2) + g * 49;
        const int kh1 = (wv == 3) ? 6 : wv + 4;
#pragma unroll
        for (int j = 0; j < 7; ++j) {
            ker[j]     = b2g[wv * 7 + j];
            ker[7 + j] = b2g[kh1 * 7 + j];
        }
        const CONST_AS float* wg = cptr(w2t) + g * 3584;
        const CONST_AS float* w0 = wg + wv * 512;
        const CONST_AS float* w1r = wg + kh1 * 512;
        const float2* tsp = (const float2*)tsw + lane;
#pragma unroll 4
        for (int o2 = 0; o2 < 32; ++o2) {
            const float2 tv = tsp[o2 * 64];                  // ds_read_b64, free
#pragma unroll
            for (int j = 0; j < 7; ++j) {                    // s_load_dwordx16 rows
                ker[j]     = fmaf(tv.x, w0[o2 * 16 + j],      ker[j]);
                ker[j]     = fmaf(tv.y, w0[o2 * 16 + 8 + j],  ker[j]);
                ker[7 + j] = fmaf(tv.x, w1r[o2 * 16 + j],     ker[7 + j]);
                ker[7 + j] = fmaf(tv.y, w1r[o2 * 16 + 8 + j], ker[7 + j]);
            }
        }
    }

    // ---- Phase B: maskless gather from zero-padded LDS ----
    float acc[16];
#pragma unroll
    for (int i = 0; i < 16; ++i) acc[i] = 0.f;

#pragma unroll
    for (int s = 0; s < 2; ++s) {
        if (wv == 3 && s == 1) break;                        // uniform
        const int row = hrel + wv + 4 * s;                   // 0..7
        const float2* xp = xs2 + row * 64 + w;
        const int kb = s * 7;
#pragma unroll
        for (int kw = 0; kw < 7; ++kw) {
            const float kv = ker[kb + kw];
#pragma unroll
            for (int c2 = 0; c2 < 8; ++c2) {
                const float2 xv = xp[c2 * 512 + kw];         // imm-offset ds_read_b64
                acc[2 * c2]     = fmaf(xv.x, kv, acc[2 * c2]);
                acc[2 * c2 + 1] = fmaf(xv.y, kv, acc[2 * c2 + 1]);
            }
        }
    }
    __syncthreads();                                         // xs/ts now dead

    // ---- cross-wave reduction: float4, stride 5 (80 B) = conflict-free ----
    float4* red4 = (float4*)smem;                            // 20 KB over xs region
#pragma unroll
    for (int q = 0; q < 4; ++q)
        red4[(wv * 64 + lane) * 5 + q] =
            make_float4(acc[4 * q], acc[4 * q + 1], acc[4 * q + 2], acc[4 * q + 3]);
    __syncthreads();

    float4 sum = red4[lane * 5 + wv];
#pragma unroll
    for (int q4 = 1; q4 < 4; ++q4) {
        const float4 r = red4[(q4 * 64 + lane) * 5 + wv];
        sum.x += r.x; sum.y += r.y; sum.z += r.z; sum.w += r.w;
    }
    float* og = out + (size_t)n * Cc * HW + (size_t)(g * 16 + wv * 4) * HW + hw;
    og[0]              = sum.x;
    og[(size_t)HW]     = sum.y;
    og[(size_t)2 * HW] = sum.z;
    og[(size_t)3 * HW] = sum.w;
}

// ---------------------------------------------------------------------------
extern "C" void kernel_launch(void* const* d_in, const int* in_sizes, int n_in,
                              void* d_out, int out_size, void* d_ws, size_t ws_size,
                              hipStream_t stream)
{
    const float* x     = (const float*)d_in[0];
    const float* w1    = (const float*)d_in[1];
    const float* b1    = (const float*)d_in[2];
    const float* gamma = (const float*)d_in[3];
    const float* beta  = (const float*)d_in[4];
    const float* mean  = (const float*)d_in[5];
    const float* var   = (const float*)d_in[6];
    const float* w2    = (const float*)d_in[7];
    const float* b2    = (const float*)d_in[8];

    float* ws  = (float*)d_ws;        // ~3.5 MB total
    float* w1f = ws + WS_W1F;
    float* bf  = ws + WS_BF;
    float* w2t = ws + WS_W2T;
    float* t   = ws + WS_T;
    float* out = (float*)d_out;

    k0_prep<<<dim3(256), 256, 0, stream>>>(
        w1, b1, gamma, beta, mean, var, w2, w1f, bf, w2t);
    k1_conv_bn_relu<<<dim3(196), 512, 0, stream>>>(x, w1f, bf, t);
    k2_involution<<<dim3(196, Gg), 256, 0, stream>>>(x, t, w2t, b2, out);
}